// Round 8
// baseline (235.842 us; speedup 1.0000x reference)
//
#include <hip/hip_runtime.h>

#define DEV __device__ __forceinline__

typedef short bf16x8 __attribute__((ext_vector_type(8)));
typedef float f32x4  __attribute__((ext_vector_type(4)));
typedef unsigned short u16;
typedef unsigned int u32;

constexpr int MTOK = 16384;
constexpr int DDIM = 1024;
constexpr int BK = 64;
constexpr int NKT = DDIM / BK;   // 16

DEV u16 f2bf(float f) {
  u32 u = __builtin_bit_cast(u32, f);
  return (u16)((u + 0x7FFFu + ((u >> 16) & 1u)) >> 16);
}

DEV void async16(const void* g, void* l) {
  __builtin_amdgcn_global_load_lds(
      (const __attribute__((address_space(1))) void*)g,
      (__attribute__((address_space(3))) void*)l, 16, 0, 0);
}

#define LGKM0()  asm volatile("s_waitcnt lgkmcnt(0)" ::: "memory")
#define VMC_(n)  asm volatile("s_waitcnt vmcnt(" #n ")" ::: "memory")
#define VMC(n)   VMC_(n)
#define SBAR()   __builtin_amdgcn_s_barrier()
#define SCH0()   __builtin_amdgcn_sched_barrier(0)

// ---------------------------------------------------------------------------
// cast_kernel: block roles. (unchanged from R6)
// ---------------------------------------------------------------------------
__global__ __launch_bounds__(256) void cast_kernel(
    const float* __restrict__ x, const float* __restrict__ Wr,
    const float* __restrict__ Wd, const float* __restrict__ Wu,
    u16* __restrict__ xh, u16* __restrict__ wrt,
    u16* __restrict__ bdh, u16* __restrict__ wuh)
{
  const int bid = blockIdx.x;
  if (bid < 1024) {
    const int base = bid * 256 + threadIdx.x;
#pragma unroll
    for (int k = 0; k < 16; ++k) {
      const size_t i = (size_t)base + (size_t)k * 262144;
      float4 v = ((const float4*)x)[i];
      ((ushort4*)xh)[i] = make_ushort4(f2bf(v.x), f2bf(v.y), f2bf(v.z), f2bf(v.w));
    }
    return;
  }
  if (bid >= 3072) {
    for (int i = threadIdx.x; i < 16384; i += 256) {
      const int e = i >> 10, d = i & 1023;
      wrt[i] = (e < 8) ? f2bf(Wr[d * 8 + e]) : (u16)0;
    }
    return;
  }
  __shared__ float tl[32][33];
  const float* src; u16* dst; int C; size_t dbase; int c0, r0;
  if (bid < 2048) {
    const int l = bid - 1024, e = l >> 7;
    src = Wd + (size_t)e * DDIM * 128; C = 128;
    dst = bdh; dbase = (size_t)e * 128 * 1024;
    c0 = (l & 3) * 32; r0 = ((l >> 2) & 31) * 32;
  } else {
    const int l = bid - 2048, e = l >> 7;
    src = Wu + (size_t)e * 128 * DDIM; C = DDIM;
    dst = wuh; dbase = (size_t)e * 128;
    c0 = (l & 31) * 32; r0 = ((l >> 5) & 3) * 32;
  }
  const int tx = threadIdx.x & 31, ty = threadIdx.x >> 5;
#pragma unroll
  for (int i = 0; i < 4; ++i)
    tl[ty + i * 8][tx] = src[(size_t)(r0 + ty + i * 8) * C + c0 + tx];
  __syncthreads();
#pragma unroll
  for (int i = 0; i < 4; ++i)
    dst[dbase + (size_t)(c0 + ty + i * 8) * 1024 + r0 + tx] = f2bf(tl[tx][ty + i * 8]);
}

// ---------------------------------------------------------------------------
// router_kernel (unchanged from R6)
// ---------------------------------------------------------------------------
__global__ __launch_bounds__(256) void router_kernel(
    const u16* __restrict__ xh, const u16* __restrict__ wrt,
    const float* __restrict__ br, float* __restrict__ probs)
{
  __shared__ float red[4][64][16];
  const int wave = threadIdx.x >> 6, lane = threadIdx.x & 63;
  const int fr = lane & 15, fq = lane >> 4;
  const int t0 = blockIdx.x * 64;
  const int k0 = wave * 256;

  f32x4 acc[4] = {};
#pragma unroll
  for (int ks = 0; ks < 8; ++ks) {
    const int kc = k0 + ks * 32 + fq * 8;
    bf16x8 b = *(const bf16x8*)&wrt[fr * 1024 + kc];
#pragma unroll
    for (int mi = 0; mi < 4; ++mi) {
      bf16x8 a = *(const bf16x8*)&xh[(size_t)(t0 + mi * 16 + fr) * 1024 + kc];
      acc[mi] = __builtin_amdgcn_mfma_f32_16x16x32_bf16(a, b, acc[mi], 0, 0, 0);
    }
  }
#pragma unroll
  for (int mi = 0; mi < 4; ++mi)
#pragma unroll
    for (int j = 0; j < 4; ++j)
      red[wave][mi * 16 + fq * 4 + j][fr] = acc[mi][j];
  __syncthreads();
  const int row = threadIdx.x;
  if (row < 64) {
    float lg[8], mx = -1e30f;
#pragma unroll
    for (int e = 0; e < 8; ++e) {
      float v = red[0][row][e] + red[1][row][e] + red[2][row][e] + red[3][row][e] + br[e];
      lg[e] = v; mx = fmaxf(mx, v);
    }
    float s = 0.f;
#pragma unroll
    for (int e = 0; e < 8; ++e) { lg[e] = expf(lg[e] - mx); s += lg[e]; }
    const float inv = 1.f / s;
#pragma unroll
    for (int e = 0; e < 8; ++e) probs[(size_t)(t0 + row) * 8 + e] = lg[e] * inv;
  }
}

// ---------------------------------------------------------------------------
// 8-phase GEMM, R6 schedule with hoisted addressing.
// All LDS-read offsets (24), stage LDS-dest offsets (8), and stage global
// voffsets (8) precomputed in registers before the K-loop; buffer parity is
// a compile-time literal (PAR = 0 / 65536) via even/odd loop peel.
// Schedule per K-tile (identical to R6, which passed):
//   P0 read A-lo+B-lo | P1 read B-hi | P2 read A-hi, stage B(t+2) |
//   P3 stage A(t+2), vmcnt(8)  — each phase: bar; lgkm0; setprio MFMA; bar.
// ---------------------------------------------------------------------------
#define MFMA(a, b, c) __builtin_amdgcn_mfma_f32_16x16x32_bf16(a, b, c, 0, 0, 0)

#define CLUSTER(MOFF, NOFF, AF, BV)                                        \
  __builtin_amdgcn_s_setprio(1);                                           \
  _Pragma("unroll") for (int k2 = 0; k2 < 2; ++k2)                         \
    _Pragma("unroll") for (int mi = 0; mi < 4; ++mi)                       \
      _Pragma("unroll") for (int ni = 0; ni < 2; ++ni)                     \
        acc[(MOFF) + mi][(NOFF) + ni] =                                    \
            MFMA(AF[k2][mi], BV[k2][ni], acc[(MOFF) + mi][(NOFF) + ni]);   \
  __builtin_amdgcn_s_setprio(0);

#define STAGE_A(T, PAR)                                                    \
  if ((T) < NKT) {                                                         \
    const int kb = (T) * 128;                                              \
    _Pragma("unroll") for (int r = 0; r < 2; ++r)                          \
      _Pragma("unroll") for (int i = 0; i < 2; ++i)                        \
        async16((const char*)A + gvo[r][i] + kb, lds + (PAR) + ldo[r][i]); \
  }

#define STAGE_B(T, PAR)                                                    \
  if ((T) < NKT) {                                                         \
    const int kb = (T) * 128;                                              \
    _Pragma("unroll") for (int r = 2; r < 4; ++r)                          \
      _Pragma("unroll") for (int i = 0; i < 2; ++i)                        \
        async16((const char*)Bm + gvo[r][i] + kb, lds + (PAR) + ldo[r][i]);\
  }

#define KT(T, PAR, VMN)                                                    \
  {                                                                        \
    bf16x8 af[2][4], blo[2][2], bhi[2][2];                                 \
    _Pragma("unroll") for (int k2 = 0; k2 < 2; ++k2) {                     \
      _Pragma("unroll") for (int mi = 0; mi < 4; ++mi)                     \
        af[k2][mi] = *(const bf16x8*)(lds + (PAR) + aoff[mi][k2]);         \
      _Pragma("unroll") for (int ni = 0; ni < 2; ++ni)                     \
        blo[k2][ni] = *(const bf16x8*)(lds + (PAR) + boff[ni][k2]);        \
    }                                                                      \
    SBAR(); LGKM0(); SCH0();                                               \
    CLUSTER(0, 0, af, blo)                                                 \
    SBAR(); SCH0();                                                        \
    _Pragma("unroll") for (int k2 = 0; k2 < 2; ++k2)                       \
      _Pragma("unroll") for (int ni = 0; ni < 2; ++ni)                     \
        bhi[k2][ni] = *(const bf16x8*)(lds + (PAR) + boff[2 + ni][k2]);    \
    SBAR(); LGKM0(); SCH0();                                               \
    CLUSTER(0, 2, af, bhi)                                                 \
    SBAR(); SCH0();                                                        \
    _Pragma("unroll") for (int k2 = 0; k2 < 2; ++k2)                       \
      _Pragma("unroll") for (int mi = 0; mi < 4; ++mi)                     \
        af[k2][mi] = *(const bf16x8*)(lds + (PAR) + aoff[4 + mi][k2]);     \
    STAGE_B((T) + 2, PAR);                                                 \
    SBAR(); LGKM0(); SCH0();                                               \
    CLUSTER(4, 2, af, bhi)                                                 \
    SBAR(); SCH0();                                                        \
    STAGE_A((T) + 2, PAR);                                                 \
    VMC(VMN); SBAR(); SCH0();                                              \
    CLUSTER(4, 0, af, blo)                                                 \
    SBAR(); SCH0();                                                        \
  }

template <int EPI>
__global__ __launch_bounds__(512, 1) void gemm8_kernel(
    const u16* __restrict__ A, const u16* __restrict__ Bm,
    const float* __restrict__ bias, const float* __restrict__ probs,
    u16* __restrict__ ogp, float* __restrict__ of)
{
  __shared__ __align__(128) char lds[131072];
  const int tid = threadIdx.x, lane = tid & 63, wave = tid >> 6;
  const int wm = wave >> 2, wn = wave & 3;         // 2 M-waves x 4 N-waves
  const int fr = lane & 15, fq = lane >> 4;

  // XCD-owned M-panels: same-A blocks co-resident on one XCD.
  const int xcd = blockIdx.x & 7, idx = blockIdx.x >> 3;
  const int m0 = (xcd * 8 + (idx & 7)) * 256;
  const int n0 = (idx >> 3) * 256;

  // ---- Hoisted addressing (all loop-invariant, registers) ----
  int aoff[8][2], boff[4][2];
#pragma unroll
  for (int mi = 0; mi < 8; ++mi)
#pragma unroll
    for (int k2 = 0; k2 < 2; ++k2) {
      const int ar = wm * 128 + mi * 16 + fr;
      aoff[mi][k2] = (ar >> 7) * 16384 + (ar & 127) * 128
                   + ((((k2 << 2) + fq) ^ (ar & 7)) << 4);
    }
#pragma unroll
  for (int ni = 0; ni < 4; ++ni)
#pragma unroll
    for (int k2 = 0; k2 < 2; ++k2) {
      const int br_ = wn * 64 + ni * 16 + fr;
      boff[ni][k2] = 32768 + (br_ >> 7) * 16384 + (br_ & 127) * 128
                   + ((((k2 << 2) + fq) ^ (br_ & 7)) << 4);
    }
  int gvo[4][2], ldo[4][2];
#pragma unroll
  for (int r = 0; r < 4; ++r)
#pragma unroll
    for (int i = 0; i < 2; ++i) {
      const int off = i * 8192 + tid * 16;
      const int row = off >> 7;
      const int sc = ((off >> 4) & 7) ^ (row & 7);
      const int rbase = ((r < 2) ? m0 : n0) + (r & 1) * 128;
      gvo[r][i] = ((rbase + row) * 1024 + sc * 8) * 2;   // bytes
      ldo[r][i] = r * 16384 + off;
    }

  f32x4 acc[8][4] = {};

  // Prologue: tiles 0 (par 0) and 1 (par 65536) fully staged; tile 0 landed.
  STAGE_A(0, 0); STAGE_B(0, 0);
  STAGE_A(1, 65536); STAGE_B(1, 65536);
  VMC(8); SBAR(); SCH0();

  for (int tt = 0; tt < NKT - 2; tt += 2) {
    KT(tt, 0, 8)
    KT(tt + 1, 65536, 8)
  }
  KT(NKT - 2, 0, 0)
  KT(NKT - 1, 65536, 0)

  if (EPI == 0) {
    const int e = (n0 + wn * 64) >> 7;
#pragma unroll
    for (int mi = 0; mi < 8; ++mi)
#pragma unroll
      for (int ni = 0; ni < 4; ++ni) {
        const int col = n0 + wn * 64 + ni * 16 + fr;
        const float bv = bias[col];
#pragma unroll
        for (int j = 0; j < 4; ++j) {
          const int row = m0 + wm * 128 + mi * 16 + fq * 4 + j;
          float v = acc[mi][ni][j] + bv;
          float g = 0.5f * v * (1.0f + erff(v * 0.70710678118654752f));
          ogp[(size_t)row * DDIM + col] = f2bf(probs[(size_t)row * 8 + e] * g);
        }
      }
  } else {
    float buv[4][8];
#pragma unroll
    for (int ni = 0; ni < 4; ++ni) {
      const int col = n0 + wn * 64 + ni * 16 + fr;
#pragma unroll
      for (int e = 0; e < 8; ++e) buv[ni][e] = bias[e * 1024 + col];
    }
#pragma unroll
    for (int mi = 0; mi < 8; ++mi)
#pragma unroll
      for (int j = 0; j < 4; ++j) {
        const int row = m0 + wm * 128 + mi * 16 + fq * 4 + j;
        const float4* pp = (const float4*)(probs + (size_t)row * 8);
        float4 p0 = pp[0], p1 = pp[1];
        float pr[8] = {p0.x, p0.y, p0.z, p0.w, p1.x, p1.y, p1.z, p1.w};
#pragma unroll
        for (int ni = 0; ni < 4; ++ni) {
          float v = acc[mi][ni][j];
#pragma unroll
          for (int e = 0; e < 8; ++e) v += pr[e] * buv[ni][e];
          of[(size_t)row * DDIM + n0 + wn * 64 + ni * 16 + fr] = v;
        }
      }
  }
}

// ---------------------------------------------------------------------------
extern "C" void kernel_launch(void* const* d_in, const int* in_sizes, int n_in,
                              void* d_out, int out_size, void* d_ws, size_t ws_size,
                              hipStream_t stream)
{
  const float* x  = (const float*)d_in[0];
  const float* Wr = (const float*)d_in[1];
  const float* br = (const float*)d_in[2];
  const float* Wd = (const float*)d_in[3];
  const float* bd = (const float*)d_in[4];
  const float* Wu = (const float*)d_in[5];
  const float* bu = (const float*)d_in[6];
  float* out = (float*)d_out;

  char* ws = (char*)d_ws;
  size_t off = 0;
  auto alloc = [&](size_t bytes) -> void* {
    void* p = ws + off;
    off += (bytes + 255) & ~(size_t)255;
    return p;
  };
  u16* xh  = (u16*)alloc((size_t)MTOK * DDIM * 2);
  u16* gph = (u16*)alloc((size_t)MTOK * 1024 * 2);
  u16* bdh = (u16*)alloc((size_t)1024 * 1024 * 2);
  u16* wuh = (u16*)alloc((size_t)1024 * 1024 * 2);
  u16* wrt = (u16*)alloc((size_t)16 * 1024 * 2);
  float* probs = (float*)alloc((size_t)MTOK * 8 * 4);
  (void)ws_size; (void)in_sizes; (void)n_in; (void)out_size;

  cast_kernel<<<3073, 256, 0, stream>>>(x, Wr, Wd, Wu, xh, wrt, bdh, wuh);
  router_kernel<<<MTOK / 64, 256, 0, stream>>>(xh, wrt, br, probs);
  gemm8_kernel<0><<<256, 512, 0, stream>>>(xh, bdh, bd, probs, gph, nullptr);
  gemm8_kernel<1><<<256, 512, 0, stream>>>(gph, wuh, bu, probs, nullptr, out);
}